// Round 1
// baseline (1097.977 us; speedup 1.0000x reference)
//
#include <hip/hip_runtime.h>

static constexpr int N_NODES = 16384;
static constexpr int N_EDGES = 262144;
static constexpr int NG = 16;

// ---------------------------------------------------------------- geometry
__global__ void k_edge_geom(const float* __restrict__ pos,
                            const int* __restrict__ src,
                            const int* __restrict__ dst,
                            float* __restrict__ ea0,
                            float* __restrict__ ea1,
                            float* __restrict__ emb) {
  int e = blockIdx.x * 256 + threadIdx.x;
  if (e >= N_EDGES) return;
  int s = src[e], d = dst[e];
  float vx = pos[s * 3 + 0] - pos[d * 3 + 0];
  float vy = pos[s * 3 + 1] - pos[d * 3 + 1];
  float vz = pos[s * 3 + 2] - pos[d * 3 + 2];
  float r = sqrtf(vx * vx + vy * vy + vz * vz + 1e-12f);
  // smooth_transition(r/2): u = r - 2
  float u = r - 2.0f;
  float y = 0.5f * (1.0f - cosf(3.14159265358979323846f * u));
  if (u > 0.0f) y = 0.0f;
  if (u < -1.0f) y = 1.0f;
  ea0[e] = y;
  float f = y * 1.7320508075688772f;  // cut * sqrt(3)
  ea1[e * 3 + 0] = f * (vx / r);
  ea1[e * 3 + 1] = f * (vy / r);
  ea1[e * 3 + 2] = f * (vz / r);
  const float step = 2.0f / 9.0f;
  const float s10 = 3.1622776601683795f;  // sqrt(10)
  #pragma unroll
  for (int j = 0; j < 10; j++) {
    float t = (r - step * (float)j) / step;
    emb[e * 10 + j] = expf(-t * t) * s10;
  }
}

// ---------------------------------------------------------------- CSR build
__global__ void k_count(const int* __restrict__ dst, int* __restrict__ cnt) {
  int e = blockIdx.x * 256 + threadIdx.x;
  if (e < N_EDGES) atomicAdd(&cnt[dst[e]], 1);
}

// single block, 1024 threads, 16 elems each. cnt_cursor is read then
// overwritten with the exclusive prefix (becomes the fill cursor).
__global__ void k_scan(int* cnt_cursor, int* __restrict__ row_start) {
  __shared__ int part[1024];
  int t = threadIdx.x;
  int base = t * 16;
  int loc[16];
  int s = 0;
  #pragma unroll
  for (int i = 0; i < 16; i++) { loc[i] = s; s += cnt_cursor[base + i]; }
  part[t] = s;
  __syncthreads();
  for (int off = 1; off < 1024; off <<= 1) {
    int v = part[t];
    int add = (t >= off) ? part[t - off] : 0;
    __syncthreads();
    part[t] = v + add;
    __syncthreads();
  }
  int excl = part[t] - s;
  #pragma unroll
  for (int i = 0; i < 16; i++) {
    int rs = excl + loc[i];
    row_start[base + i] = rs;
    cnt_cursor[base + i] = rs;
  }
  if (t == 1023) row_start[N_NODES] = part[1023];
}

__global__ void k_fill(const int* __restrict__ dst, int* cursor,
                       int* __restrict__ edge_ids) {
  int e = blockIdx.x * 256 + threadIdx.x;
  if (e < N_EDGES) {
    int p = atomicAdd(&cursor[dst[e]], 1);
    edge_ids[p] = e;
  }
}

// ---------------------------------------------------------------- radial MLP
// Fused emb(10) -> relu(h(100)) -> W(C) for a 64-edge tile per 256-thread block.
template <int C>
__global__ void k_radial(const float* __restrict__ emb,
                         const float* __restrict__ w1,   // (10,100)
                         const float* __restrict__ w2,   // (100,C)
                         float* __restrict__ W) {        // (E,C)
  __shared__ float emb_s[64][10];
  __shared__ float h_s[64][101];  // pad 101: stride 5 banks -> conflict-free-ish
  int tid = threadIdx.x;
  int e0 = blockIdx.x * 64;
  for (int i = tid; i < 640; i += 256)
    emb_s[i / 10][i % 10] = emb[(size_t)e0 * 10 + i];
  __syncthreads();
  {
    int e = tid & 63, q = tid >> 6;
    float er[10];
    #pragma unroll
    for (int i = 0; i < 10; i++) er[i] = emb_s[e][i];
    const float inv_s10 = 0.31622776601683794f;  // 1/sqrt(10)
    for (int j = 0; j < 25; j++) {
      int k = q * 25 + j;
      float acc = 0.f;
      #pragma unroll
      for (int i = 0; i < 10; i++) acc += er[i] * w1[i * 100 + k];
      h_s[e][k] = fmaxf(acc * inv_s10, 0.f);
    }
  }
  __syncthreads();
  int c_lane = tid & 15, es = tid >> 4;
  for (int cb = 0; cb < C / 16; cb++) {
    int c = cb * 16 + c_lane;
    float a0 = 0.f, a1 = 0.f, a2 = 0.f, a3 = 0.f;
    for (int k = 0; k < 100; k++) {
      float wv = w2[k * C + c];
      a0 += h_s[es +  0][k] * wv;
      a1 += h_s[es + 16][k] * wv;
      a2 += h_s[es + 32][k] * wv;
      a3 += h_s[es + 48][k] * wv;
    }
    W[(size_t)(e0 + es +  0) * C + c] = a0 * 0.1f;  // /sqrt(100)
    W[(size_t)(e0 + es + 16) * C + c] = a1 * 0.1f;
    W[(size_t)(e0 + es + 32) * C + c] = a2 * 0.1f;
    W[(size_t)(e0 + es + 48) * C + c] = a3 * 0.1f;
  }
}

// ---------------------------------------------------------------- node linears
// layer0: x(N,16) -> si0(N,80), y0(N,16)
__global__ void k_pre0(const float* __restrict__ x, const float* __restrict__ z,
                       const float* __restrict__ si_w,  // (80,16)
                       const float* __restrict__ l1_w,  // (16,16)
                       float* __restrict__ si0b, float* __restrict__ y0b) {
  int v = (blockIdx.x * 256 + threadIdx.x) >> 6;
  int t = threadIdx.x & 63;
  float zv = z[v];
  float xz[16];
  #pragma unroll
  for (int i = 0; i < 16; i++) xz[i] = x[v * 16 + i] * zv;
  float a = 0.f;
  #pragma unroll
  for (int k = 0; k < 16; k++) a += si_w[t * 16 + k] * xz[k];
  si0b[v * 80 + t] = a * 0.25f;
  if (t < 16) {
    float a2 = 0.f, a3 = 0.f;
    #pragma unroll
    for (int k = 0; k < 16; k++) {
      a2 += si_w[(64 + t) * 16 + k] * xz[k];
      a3 += l1_w[t * 16 + k] * xz[k];
    }
    si0b[v * 80 + 64 + t] = a2 * 0.25f;
    y0b[v * 16 + t] = a3 * 0.25f;
  }
}

// layer1: h0(N,64),h1(N,16,3) -> si0(N,80), y0(N,64), si1(N,16,3), y1(N,16,3)
__global__ void k_pre1(const float* __restrict__ h0, const float* __restrict__ h1,
                       const float* __restrict__ z,
                       const float* __restrict__ si_w0,  // (80,64)
                       const float* __restrict__ si_w1,  // (16,16)
                       const float* __restrict__ l1_w0,  // (64,64)
                       const float* __restrict__ l1_w1,  // (16,16)
                       float* __restrict__ si0b, float* __restrict__ y0b,
                       float* __restrict__ si1b, float* __restrict__ y1b) {
  __shared__ float xs[4][64];
  int v = (blockIdx.x * 256 + threadIdx.x) >> 6;
  int w = threadIdx.x >> 6;
  int t = threadIdx.x & 63;
  float zv = z[v];
  xs[w][t] = h0[v * 64 + t] * zv;
  __syncthreads();
  const float* x0 = xs[w];
  float a0 = 0.f, ay = 0.f;
  for (int k = 0; k < 64; k++) {
    float xv = x0[k];
    a0 += si_w0[t * 64 + k] * xv;
    ay += l1_w0[t * 64 + k] * xv;
  }
  si0b[v * 80 + t] = a0 * 0.125f;
  y0b[v * 64 + t] = ay * 0.125f;
  if (t < 16) {
    float a2 = 0.f;
    for (int k = 0; k < 64; k++) a2 += si_w0[(64 + t) * 64 + k] * x0[k];
    si0b[v * 80 + 64 + t] = a2 * 0.125f;
    #pragma unroll
    for (int m = 0; m < 3; m++) {
      float s = 0.f, yy = 0.f;
      #pragma unroll
      for (int vv = 0; vv < 16; vv++) {
        float xv = h1[v * 48 + vv * 3 + m] * zv;
        s += si_w1[t * 16 + vv] * xv;
        yy += l1_w1[t * 16 + vv] * xv;
      }
      si1b[v * 48 + t * 3 + m] = s * 0.25f;
      y1b[v * 48 + t * 3 + m] = yy * 0.25f;
    }
  }
}

// final: h0(N,64),h1(N,16,3) -> si0(N,1), y0(N,64), y1(N,16,3)
__global__ void k_preF(const float* __restrict__ h0, const float* __restrict__ h1,
                       const float* __restrict__ z,
                       const float* __restrict__ si_w0,  // (1,64)
                       const float* __restrict__ l1_w0,  // (64,64)
                       const float* __restrict__ l1_w1,  // (16,16)
                       float* __restrict__ si0b, float* __restrict__ y0b,
                       float* __restrict__ y1b) {
  __shared__ float xs[4][64];
  int v = (blockIdx.x * 256 + threadIdx.x) >> 6;
  int w = threadIdx.x >> 6;
  int t = threadIdx.x & 63;
  float zv = z[v];
  xs[w][t] = h0[v * 64 + t] * zv;
  __syncthreads();
  const float* x0 = xs[w];
  float ay = 0.f;
  for (int k = 0; k < 64; k++) ay += l1_w0[t * 64 + k] * x0[k];
  y0b[v * 64 + t] = ay * 0.125f;
  if (t == 0) {
    float a = 0.f;
    for (int k = 0; k < 64; k++) a += si_w0[k] * x0[k];
    si0b[v] = a * 0.125f;
  }
  if (t < 16) {
    #pragma unroll
    for (int m = 0; m < 3; m++) {
      float yy = 0.f;
      #pragma unroll
      for (int vv = 0; vv < 16; vv++)
        yy += l1_w1[t * 16 + vv] * h1[v * 48 + vv * 3 + m] * zv;
      y1b[v * 48 + t * 3 + m] = yy * 0.25f;
    }
  }
}

// ---------------------------------------------------------------- messages
// layer0: one wave per node, 4 edges in flight (lanes = 4 edge-slots x 16 ch)
__global__ void k_msg0(const int* __restrict__ rs, const int* __restrict__ eid,
                       const int* __restrict__ src,
                       const float* __restrict__ W,    // (E,32)
                       const float* __restrict__ y0,   // (N,16)
                       const float* __restrict__ ea0, const float* __restrict__ ea1,
                       float* __restrict__ s0,         // (N,16)
                       float* __restrict__ s1) {       // (N,16,3)
  int v = (blockIdx.x * 256 + threadIdx.x) >> 6;
  int t = threadIdx.x & 63;
  int u = t & 15, es = t >> 4;
  int b = rs[v], eend = rs[v + 1];
  float a0 = 0.f, a1x = 0.f, a1y = 0.f, a1z = 0.f;
  for (int idx = b + es; idx < eend; idx += 4) {
    int e = eid[idx];
    int s = src[e];
    float wa = W[(size_t)e * 32 + u];
    float wb = W[(size_t)e * 32 + 16 + u];
    float g0 = y0[s * 16 + u];
    float c0 = ea0[e];
    float cx = ea1[e * 3 + 0], cy = ea1[e * 3 + 1], cz = ea1[e * 3 + 2];
    a0 += wa * g0 * c0;
    float wg = wb * g0;
    a1x += wg * cx; a1y += wg * cy; a1z += wg * cz;
  }
  a0  += __shfl_xor(a0, 16, 64);  a0  += __shfl_xor(a0, 32, 64);
  a1x += __shfl_xor(a1x, 16, 64); a1x += __shfl_xor(a1x, 32, 64);
  a1y += __shfl_xor(a1y, 16, 64); a1y += __shfl_xor(a1y, 32, 64);
  a1z += __shfl_xor(a1z, 16, 64); a1z += __shfl_xor(a1z, 32, 64);
  if (es == 0) {
    s0[v * 16 + u] = a0 * 0.25f;
    s1[v * 48 + u * 3 + 0] = a1x * 0.25f;
    s1[v * 48 + u * 3 + 1] = a1y * 0.25f;
    s1[v * 48 + u * 3 + 2] = a1z * 0.25f;
  }
}

// layer1: one wave per node; lane t owns ch t (A/B) and ch 64+t for t<16 (C/D)
__global__ void k_msg1(const int* __restrict__ rs, const int* __restrict__ eid,
                       const int* __restrict__ src,
                       const float* __restrict__ W,    // (E,160)
                       const float* __restrict__ y0,   // (N,64)
                       const float* __restrict__ y1,   // (N,16,3)
                       const float* __restrict__ ea0, const float* __restrict__ ea1,
                       float* __restrict__ s0,         // (N,80)
                       float* __restrict__ s1) {       // (N,80,3)
  int v = (blockIdx.x * 256 + threadIdx.x) >> 6;
  int t = threadIdx.x & 63;
  int b = rs[v], eend = rs[v + 1];
  const float inv_sq3 = 0.5773502691896258f;
  float a0A = 0.f, a0D = 0.f;
  float aB0 = 0.f, aB1 = 0.f, aB2 = 0.f;
  float aC0 = 0.f, aC1 = 0.f, aC2 = 0.f;
  for (int idx = b; idx < eend; idx++) {
    int e = eid[idx];
    int s = src[e];
    float wa = W[(size_t)e * 160 + t];
    float wb = W[(size_t)e * 160 + 64 + t];
    float g0 = y0[s * 64 + t];
    float c0 = ea0[e];
    float cx = ea1[e * 3 + 0], cy = ea1[e * 3 + 1], cz = ea1[e * 3 + 2];
    a0A += wa * g0 * c0;
    float wg = wb * g0;
    aB0 += wg * cx; aB1 += wg * cy; aB2 += wg * cz;
    if (t < 16) {
      float wc = W[(size_t)e * 160 + 128 + t];
      float wd = W[(size_t)e * 160 + 144 + t];
      float g1x = y1[s * 48 + t * 3 + 0];
      float g1y = y1[s * 48 + t * 3 + 1];
      float g1z = y1[s * 48 + t * 3 + 2];
      a0D += wd * (g1x * cx + g1y * cy + g1z * cz) * inv_sq3;
      aC0 += wc * g1x * c0; aC1 += wc * g1y * c0; aC2 += wc * g1z * c0;
    }
  }
  s0[v * 80 + t] = a0A * 0.25f;
  s1[v * 240 + t * 3 + 0] = aB0 * 0.25f;
  s1[v * 240 + t * 3 + 1] = aB1 * 0.25f;
  s1[v * 240 + t * 3 + 2] = aB2 * 0.25f;
  if (t < 16) {
    s0[v * 80 + 64 + t] = a0D * 0.25f;
    s1[v * 240 + (64 + t) * 3 + 0] = aC0 * 0.25f;
    s1[v * 240 + (64 + t) * 3 + 1] = aC1 * 0.25f;
    s1[v * 240 + (64 + t) * 3 + 2] = aC2 * 0.25f;
  }
}

// final: mid0 only
__global__ void k_msgF(const int* __restrict__ rs, const int* __restrict__ eid,
                       const int* __restrict__ src,
                       const float* __restrict__ W,    // (E,80)
                       const float* __restrict__ y0,   // (N,64)
                       const float* __restrict__ y1,   // (N,16,3)
                       const float* __restrict__ ea0, const float* __restrict__ ea1,
                       float* __restrict__ s0) {       // (N,80)
  int v = (blockIdx.x * 256 + threadIdx.x) >> 6;
  int t = threadIdx.x & 63;
  int b = rs[v], eend = rs[v + 1];
  const float inv_sq3 = 0.5773502691896258f;
  float a0A = 0.f, a0D = 0.f;
  for (int idx = b; idx < eend; idx++) {
    int e = eid[idx];
    int s = src[e];
    float wa = W[(size_t)e * 80 + t];
    float g0 = y0[s * 64 + t];
    float c0 = ea0[e];
    a0A += wa * g0 * c0;
    if (t < 16) {
      float wd = W[(size_t)e * 80 + 64 + t];
      float cx = ea1[e * 3 + 0], cy = ea1[e * 3 + 1], cz = ea1[e * 3 + 2];
      float g1x = y1[s * 48 + t * 3 + 0];
      float g1y = y1[s * 48 + t * 3 + 1];
      float g1z = y1[s * 48 + t * 3 + 2];
      a0D += wd * (g1x * cx + g1y * cy + g1z * cz) * inv_sq3;
    }
  }
  s0[v * 80 + t] = a0A * 0.25f;
  if (t < 16) s0[v * 80 + 64 + t] = a0D * 0.25f;
}

// ---------------------------------------------------------------- epilogues
// layer0: out0 = si0 + 0.5*lin0(s0,w0) [/4]; o1 = 0.5*lin1(s1,w1) [/4]; gate
__global__ void k_epi0(const float* __restrict__ s0,    // (N,16)
                       const float* __restrict__ s1,    // (N,16,3)
                       const float* __restrict__ si0b,  // (N,80)
                       const float* __restrict__ w0,    // (80,16)
                       const float* __restrict__ w1,    // (16,16)
                       float* __restrict__ h0, float* __restrict__ h1) {
  int v = (blockIdx.x * 256 + threadIdx.x) >> 6;
  int t = threadIdx.x & 63;
  float s0r[16];
  #pragma unroll
  for (int k = 0; k < 16; k++) s0r[k] = s0[v * 16 + k];
  float a = 0.f;
  #pragma unroll
  for (int k = 0; k < 16; k++) a += w0[t * 16 + k] * s0r[k];
  float o = si0b[v * 80 + t] + 0.125f * a;
  h0[v * 64 + t] = fmaxf(o, 0.f);
  if (t < 16) {
    float a2 = 0.f;
    #pragma unroll
    for (int k = 0; k < 16; k++) a2 += w0[(64 + t) * 16 + k] * s0r[k];
    float g = fmaxf(si0b[v * 80 + 64 + t] + 0.125f * a2, 0.f);
    #pragma unroll
    for (int m = 0; m < 3; m++) {
      float ac = 0.f;
      #pragma unroll
      for (int vv = 0; vv < 16; vv++) ac += w1[t * 16 + vv] * s1[v * 48 + vv * 3 + m];
      h1[v * 48 + t * 3 + m] = (0.125f * ac) * g;
    }
  }
}

// layer1: /sqrt(80) norms, si1 present
__global__ void k_epi1(const float* __restrict__ s0,    // (N,80)
                       const float* __restrict__ s1,    // (N,80,3)
                       const float* __restrict__ si0b,  // (N,80)
                       const float* __restrict__ si1b,  // (N,16,3)
                       const float* __restrict__ w0,    // (80,80)
                       const float* __restrict__ w1,    // (16,80)
                       float* __restrict__ h0, float* __restrict__ h1) {
  int v = (blockIdx.x * 256 + threadIdx.x) >> 6;
  int t = threadIdx.x & 63;
  const float sc = 0.05590169943749474f;  // 0.5/sqrt(80)
  float a = 0.f;
  for (int k = 0; k < 80; k++) a += w0[t * 80 + k] * s0[v * 80 + k];
  float o = si0b[v * 80 + t] + sc * a;
  h0[v * 64 + t] = fmaxf(o, 0.f);
  if (t < 16) {
    float a2 = 0.f;
    for (int k = 0; k < 80; k++) a2 += w0[(64 + t) * 80 + k] * s0[v * 80 + k];
    float g = fmaxf(si0b[v * 80 + 64 + t] + sc * a2, 0.f);
    #pragma unroll
    for (int m = 0; m < 3; m++) {
      float ac = 0.f;
      for (int vv = 0; vv < 80; vv++) ac += w1[t * 80 + vv] * s1[v * 240 + vv * 3 + m];
      h1[v * 48 + t * 3 + m] = (si1b[v * 48 + t * 3 + m] + sc * ac) * g;
    }
  }
}

// final: out0(N,1) then segment-sum over batch /32
__global__ void k_epiF(const float* __restrict__ s0,    // (N,80)
                       const float* __restrict__ si0b,  // (N,1)
                       const float* __restrict__ w0,    // (1,80)
                       const int* __restrict__ batch,
                       float* __restrict__ out) {
  __shared__ float sm[NG];
  int tid = threadIdx.x;
  int n = blockIdx.x * 256 + tid;
  if (tid < NG) sm[tid] = 0.f;
  __syncthreads();
  const float sc = 0.05590169943749474f;  // 0.5/sqrt(80)
  float a = 0.f;
  for (int k = 0; k < 80; k++) a += w0[k] * s0[n * 80 + k];
  float val = si0b[n] + sc * a;
  atomicAdd(&sm[batch[n]], val);
  __syncthreads();
  if (tid < NG) atomicAdd(&out[tid], sm[tid] * 0.03125f);  // /sqrt(1024)
}

// ---------------------------------------------------------------- launch
extern "C" void kernel_launch(void* const* d_in, const int* in_sizes, int n_in,
                              void* d_out, int out_size, void* d_ws, size_t ws_size,
                              hipStream_t stream) {
  const float* x        = (const float*)d_in[0];
  const float* z        = (const float*)d_in[1];
  const float* pos      = (const float*)d_in[2];
  const float* fc0_w1   = (const float*)d_in[3];
  const float* fc0_w2   = (const float*)d_in[4];
  const float* si0_w    = (const float*)d_in[5];
  const float* l0_l1_w  = (const float*)d_in[6];
  const float* l0_l2_w0 = (const float*)d_in[7];
  const float* l0_l2_w1 = (const float*)d_in[8];
  const float* fc1_w1   = (const float*)d_in[9];
  const float* fc1_w2   = (const float*)d_in[10];
  const float* si1_w0   = (const float*)d_in[11];
  const float* si1_w1   = (const float*)d_in[12];
  const float* l1_l1_w0 = (const float*)d_in[13];
  const float* l1_l1_w1 = (const float*)d_in[14];
  const float* l1_l2_w0 = (const float*)d_in[15];
  const float* l1_l2_w1 = (const float*)d_in[16];
  const float* fcf_w1   = (const float*)d_in[17];
  const float* fcf_w2   = (const float*)d_in[18];
  const float* sif_w0   = (const float*)d_in[19];
  const float* lf_l1_w0 = (const float*)d_in[20];
  const float* lf_l1_w1 = (const float*)d_in[21];
  const float* lf_l2_w0 = (const float*)d_in[22];
  const int*   esrc     = (const int*)d_in[23];
  const int*   edst     = (const int*)d_in[24];
  const int*   batch    = (const int*)d_in[25];
  float* out = (float*)d_out;

  // workspace carve (floats): ~228 MB total
  float* p = (float*)d_ws;
  float* ea0  = p; p += (size_t)N_EDGES;
  float* ea1  = p; p += (size_t)3 * N_EDGES;
  float* emb  = p; p += (size_t)10 * N_EDGES;
  float* W    = p; p += (size_t)160 * N_EDGES;
  float* si0b = p; p += (size_t)80 * N_NODES;
  float* y0b  = p; p += (size_t)64 * N_NODES;
  float* si1b = p; p += (size_t)48 * N_NODES;
  float* y1b  = p; p += (size_t)48 * N_NODES;
  float* s0   = p; p += (size_t)80 * N_NODES;
  float* s1   = p; p += (size_t)240 * N_NODES;
  float* h0   = p; p += (size_t)64 * N_NODES;
  float* h1   = p; p += (size_t)48 * N_NODES;
  int* cnt   = (int*)p;
  int* rowst = cnt + N_NODES;
  int* eids  = rowst + N_NODES + 1;

  hipMemsetAsync(cnt, 0, N_NODES * sizeof(int), stream);
  hipMemsetAsync(d_out, 0, NG * sizeof(float), stream);

  k_edge_geom<<<N_EDGES / 256, 256, 0, stream>>>(pos, esrc, edst, ea0, ea1, emb);
  k_count<<<N_EDGES / 256, 256, 0, stream>>>(edst, cnt);
  k_scan<<<1, 1024, 0, stream>>>(cnt, rowst);
  k_fill<<<N_EDGES / 256, 256, 0, stream>>>(edst, cnt, eids);

  const int NWG = N_NODES / 4;  // wave-per-node kernels: 4 waves / 256-thread block

  // ---- layer 0
  k_pre0<<<NWG, 256, 0, stream>>>(x, z, si0_w, l0_l1_w, si0b, y0b);
  k_radial<32><<<N_EDGES / 64, 256, 0, stream>>>(emb, fc0_w1, fc0_w2, W);
  k_msg0<<<NWG, 256, 0, stream>>>(rowst, eids, esrc, W, y0b, ea0, ea1, s0, s1);
  k_epi0<<<NWG, 256, 0, stream>>>(s0, s1, si0b, l0_l2_w0, l0_l2_w1, h0, h1);

  // ---- layer 1
  k_pre1<<<NWG, 256, 0, stream>>>(h0, h1, z, si1_w0, si1_w1, l1_l1_w0, l1_l1_w1,
                                  si0b, y0b, si1b, y1b);
  k_radial<160><<<N_EDGES / 64, 256, 0, stream>>>(emb, fc1_w1, fc1_w2, W);
  k_msg1<<<NWG, 256, 0, stream>>>(rowst, eids, esrc, W, y0b, y1b, ea0, ea1, s0, s1);
  k_epi1<<<NWG, 256, 0, stream>>>(s0, s1, si0b, si1b, l1_l2_w0, l1_l2_w1, h0, h1);

  // ---- final layer
  k_preF<<<NWG, 256, 0, stream>>>(h0, h1, z, sif_w0, lf_l1_w0, lf_l1_w1,
                                  si0b, y0b, y1b);
  k_radial<80><<<N_EDGES / 64, 256, 0, stream>>>(emb, fcf_w1, fcf_w2, W);
  k_msgF<<<NWG, 256, 0, stream>>>(rowst, eids, esrc, W, y0b, y1b, ea0, ea1, s0);
  k_epiF<<<N_NODES / 256, 256, 0, stream>>>(s0, si0b, lf_l2_w0, batch, out);
}

// Round 2
// 947.152 us; speedup vs baseline: 1.1592x; 1.1592x over previous
//
#include <hip/hip_runtime.h>

static constexpr int N_NODES = 16384;
static constexpr int N_EDGES = 262144;
static constexpr int NG = 16;

// ---------------------------------------------------------------- geometry (+ degree count)
__global__ void k_edge_geom(const float* __restrict__ pos,
                            const int* __restrict__ src,
                            const int* __restrict__ dst,
                            float* __restrict__ ea0,
                            float* __restrict__ ea1,
                            float* __restrict__ emb,
                            int* __restrict__ cnt) {
  int e = blockIdx.x * 256 + threadIdx.x;
  if (e >= N_EDGES) return;
  int s = src[e], d = dst[e];
  float vx = pos[s * 3 + 0] - pos[d * 3 + 0];
  float vy = pos[s * 3 + 1] - pos[d * 3 + 1];
  float vz = pos[s * 3 + 2] - pos[d * 3 + 2];
  float r = sqrtf(vx * vx + vy * vy + vz * vz + 1e-12f);
  // smooth_transition(r/2): u = r - 2
  float u = r - 2.0f;
  float y = 0.5f * (1.0f - cosf(3.14159265358979323846f * u));
  if (u > 0.0f) y = 0.0f;
  if (u < -1.0f) y = 1.0f;
  ea0[e] = y;
  float f = y * 1.7320508075688772f;  // cut * sqrt(3)
  ea1[e * 3 + 0] = f * (vx / r);
  ea1[e * 3 + 1] = f * (vy / r);
  ea1[e * 3 + 2] = f * (vz / r);
  const float step = 2.0f / 9.0f;
  const float s10 = 3.1622776601683795f;  // sqrt(10)
  #pragma unroll
  for (int j = 0; j < 10; j++) {
    float t = (r - step * (float)j) / step;
    emb[e * 10 + j] = expf(-t * t) * s10;
  }
  atomicAdd(&cnt[d], 1);
}

// ---------------------------------------------------------------- CSR build
// single block, 1024 threads, 16 elems each. cnt_cursor is read then
// overwritten with the exclusive prefix (becomes the fill cursor).
__global__ void k_scan(int* cnt_cursor, int* __restrict__ row_start) {
  __shared__ int part[1024];
  int t = threadIdx.x;
  int base = t * 16;
  int loc[16];
  int s = 0;
  #pragma unroll
  for (int i = 0; i < 16; i++) { loc[i] = s; s += cnt_cursor[base + i]; }
  part[t] = s;
  __syncthreads();
  for (int off = 1; off < 1024; off <<= 1) {
    int v = part[t];
    int add = (t >= off) ? part[t - off] : 0;
    __syncthreads();
    part[t] = v + add;
    __syncthreads();
  }
  int excl = part[t] - s;
  #pragma unroll
  for (int i = 0; i < 16; i++) {
    int rs = excl + loc[i];
    row_start[base + i] = rs;
    cnt_cursor[base + i] = rs;
  }
  if (t == 1023) row_start[N_NODES] = part[1023];
}

__global__ void k_fill(const int* __restrict__ dst, int* cursor,
                       int* __restrict__ edge_ids) {
  int e = blockIdx.x * 256 + threadIdx.x;
  if (e < N_EDGES) {
    int p = atomicAdd(&cursor[dst[e]], 1);
    edge_ids[p] = e;
  }
}

// ---------------------------------------------------------------- radial MLP
// Fused emb(10) -> relu(h(100)) -> W(C) for a 64-edge tile per 256-thread block.
// Stage 2 is register-blocked: thread tile = 4 edges x (C/16) channels,
// channels interleaved (c = cg + 16j) for coalesced w2 loads / W stores,
// h read as float4 from 16B-aligned LDS rows (k unrolled x4).
template <int C>
__global__ __launch_bounds__(256) void k_radial(
    const float* __restrict__ emb,
    const float* __restrict__ w1,   // (10,100)
    const float* __restrict__ w2,   // (100,C)
    float* __restrict__ W) {        // (E,C)
  constexpr int TC = C / 16;
  __shared__ float emb_s[64][10];
  __shared__ __attribute__((aligned(16))) float h_s[64][100];  // 400B rows, 16B aligned
  int tid = threadIdx.x;
  int e0 = blockIdx.x * 64;
  for (int i = tid; i < 640; i += 256)
    emb_s[i / 10][i % 10] = emb[(size_t)e0 * 10 + i];
  __syncthreads();
  {
    int e = tid & 63, q = tid >> 6;  // k uniform per wave -> w1 loads are scalar
    float er[10];
    #pragma unroll
    for (int i = 0; i < 10; i++) er[i] = emb_s[e][i];
    const float inv_s10 = 0.31622776601683794f;  // 1/sqrt(10)
    #pragma unroll
    for (int j = 0; j < 25; j++) {
      int k = q * 25 + j;
      float acc = 0.f;
      #pragma unroll
      for (int i = 0; i < 10; i++) acc += er[i] * w1[i * 100 + k];
      h_s[e][k] = fmaxf(acc * inv_s10, 0.f);
    }
  }
  __syncthreads();
  int cg = tid & 15, eg = tid >> 4;
  float acc[4][TC];
  #pragma unroll
  for (int i = 0; i < 4; i++)
    #pragma unroll
    for (int j = 0; j < TC; j++) acc[i][j] = 0.f;

  for (int k4 = 0; k4 < 25; k4++) {
    float hv[4][4];
    #pragma unroll
    for (int i = 0; i < 4; i++) {
      float4 t4 = *reinterpret_cast<const float4*>(&h_s[eg * 4 + i][k4 * 4]);
      hv[i][0] = t4.x; hv[i][1] = t4.y; hv[i][2] = t4.z; hv[i][3] = t4.w;
    }
    #pragma unroll
    for (int kk = 0; kk < 4; kk++) {
      const float* w2k = w2 + (k4 * 4 + kk) * C + cg;
      float w2r[TC];
      #pragma unroll
      for (int j = 0; j < TC; j++) w2r[j] = w2k[16 * j];
      #pragma unroll
      for (int i = 0; i < 4; i++)
        #pragma unroll
        for (int j = 0; j < TC; j++) acc[i][j] += hv[i][kk] * w2r[j];
    }
  }
  #pragma unroll
  for (int i = 0; i < 4; i++) {
    float* Wrow = W + (size_t)(e0 + eg * 4 + i) * C + cg;
    #pragma unroll
    for (int j = 0; j < TC; j++) Wrow[16 * j] = acc[i][j] * 0.1f;  // /sqrt(100)
  }
}

// ---------------------------------------------------------------- node linears
// layer0: x(N,16) -> si0(N,80), y0(N,16)
__global__ void k_pre0(const float* __restrict__ x, const float* __restrict__ z,
                       const float* __restrict__ si_w,  // (80,16)
                       const float* __restrict__ l1_w,  // (16,16)
                       float* __restrict__ si0b, float* __restrict__ y0b) {
  int v = (blockIdx.x * 256 + threadIdx.x) >> 6;
  int t = threadIdx.x & 63;
  float zv = z[v];
  float xz[16];
  #pragma unroll
  for (int i = 0; i < 16; i++) xz[i] = x[v * 16 + i] * zv;
  float a = 0.f;
  #pragma unroll
  for (int k = 0; k < 16; k++) a += si_w[t * 16 + k] * xz[k];
  si0b[v * 80 + t] = a * 0.25f;
  if (t < 16) {
    float a2 = 0.f, a3 = 0.f;
    #pragma unroll
    for (int k = 0; k < 16; k++) {
      a2 += si_w[(64 + t) * 16 + k] * xz[k];
      a3 += l1_w[t * 16 + k] * xz[k];
    }
    si0b[v * 80 + 64 + t] = a2 * 0.25f;
    y0b[v * 16 + t] = a3 * 0.25f;
  }
}

// layer1: h0(N,64),h1(N,16,3) -> si0(N,80), y0(N,64), si1(N,16,3), y1(N,16,3)
__global__ void k_pre1(const float* __restrict__ h0, const float* __restrict__ h1,
                       const float* __restrict__ z,
                       const float* __restrict__ si_w0,  // (80,64)
                       const float* __restrict__ si_w1,  // (16,16)
                       const float* __restrict__ l1_w0,  // (64,64)
                       const float* __restrict__ l1_w1,  // (16,16)
                       float* __restrict__ si0b, float* __restrict__ y0b,
                       float* __restrict__ si1b, float* __restrict__ y1b) {
  __shared__ float xs[4][64];
  int v = (blockIdx.x * 256 + threadIdx.x) >> 6;
  int w = threadIdx.x >> 6;
  int t = threadIdx.x & 63;
  float zv = z[v];
  xs[w][t] = h0[v * 64 + t] * zv;
  __syncthreads();
  const float* x0 = xs[w];
  float a0 = 0.f, ay = 0.f;
  for (int k = 0; k < 64; k++) {
    float xv = x0[k];
    a0 += si_w0[t * 64 + k] * xv;
    ay += l1_w0[t * 64 + k] * xv;
  }
  si0b[v * 80 + t] = a0 * 0.125f;
  y0b[v * 64 + t] = ay * 0.125f;
  if (t < 16) {
    float a2 = 0.f;
    for (int k = 0; k < 64; k++) a2 += si_w0[(64 + t) * 64 + k] * x0[k];
    si0b[v * 80 + 64 + t] = a2 * 0.125f;
    #pragma unroll
    for (int m = 0; m < 3; m++) {
      float s = 0.f, yy = 0.f;
      #pragma unroll
      for (int vv = 0; vv < 16; vv++) {
        float xv = h1[v * 48 + vv * 3 + m] * zv;
        s += si_w1[t * 16 + vv] * xv;
        yy += l1_w1[t * 16 + vv] * xv;
      }
      si1b[v * 48 + t * 3 + m] = s * 0.25f;
      y1b[v * 48 + t * 3 + m] = yy * 0.25f;
    }
  }
}

// final: h0(N,64),h1(N,16,3) -> si0(N,1), y0(N,64), y1(N,16,3)
__global__ void k_preF(const float* __restrict__ h0, const float* __restrict__ h1,
                       const float* __restrict__ z,
                       const float* __restrict__ si_w0,  // (1,64)
                       const float* __restrict__ l1_w0,  // (64,64)
                       const float* __restrict__ l1_w1,  // (16,16)
                       float* __restrict__ si0b, float* __restrict__ y0b,
                       float* __restrict__ y1b) {
  __shared__ float xs[4][64];
  int v = (blockIdx.x * 256 + threadIdx.x) >> 6;
  int w = threadIdx.x >> 6;
  int t = threadIdx.x & 63;
  float zv = z[v];
  xs[w][t] = h0[v * 64 + t] * zv;
  __syncthreads();
  const float* x0 = xs[w];
  float ay = 0.f;
  for (int k = 0; k < 64; k++) ay += l1_w0[t * 64 + k] * x0[k];
  y0b[v * 64 + t] = ay * 0.125f;
  if (t == 0) {
    float a = 0.f;
    for (int k = 0; k < 64; k++) a += si_w0[k] * x0[k];
    si0b[v] = a * 0.125f;
  }
  if (t < 16) {
    #pragma unroll
    for (int m = 0; m < 3; m++) {
      float yy = 0.f;
      #pragma unroll
      for (int vv = 0; vv < 16; vv++)
        yy += l1_w1[t * 16 + vv] * h1[v * 48 + vv * 3 + m] * zv;
      y1b[v * 48 + t * 3 + m] = yy * 0.25f;
    }
  }
}

// ---------------------------------------------------------------- messages
// layer0: one wave per node, 4 edges in flight (lanes = 4 edge-slots x 16 ch)
__global__ void k_msg0(const int* __restrict__ rs, const int* __restrict__ eid,
                       const int* __restrict__ src,
                       const float* __restrict__ W,    // (E,32)
                       const float* __restrict__ y0,   // (N,16)
                       const float* __restrict__ ea0, const float* __restrict__ ea1,
                       float* __restrict__ s0,         // (N,16)
                       float* __restrict__ s1) {       // (N,16,3)
  int v = (blockIdx.x * 256 + threadIdx.x) >> 6;
  int t = threadIdx.x & 63;
  int u = t & 15, es = t >> 4;
  int b = rs[v], eend = rs[v + 1];
  float a0 = 0.f, a1x = 0.f, a1y = 0.f, a1z = 0.f;
  for (int idx = b + es; idx < eend; idx += 4) {
    int e = eid[idx];
    int s = src[e];
    float wa = W[(size_t)e * 32 + u];
    float wb = W[(size_t)e * 32 + 16 + u];
    float g0 = y0[s * 16 + u];
    float c0 = ea0[e];
    float cx = ea1[e * 3 + 0], cy = ea1[e * 3 + 1], cz = ea1[e * 3 + 2];
    a0 += wa * g0 * c0;
    float wg = wb * g0;
    a1x += wg * cx; a1y += wg * cy; a1z += wg * cz;
  }
  a0  += __shfl_xor(a0, 16, 64);  a0  += __shfl_xor(a0, 32, 64);
  a1x += __shfl_xor(a1x, 16, 64); a1x += __shfl_xor(a1x, 32, 64);
  a1y += __shfl_xor(a1y, 16, 64); a1y += __shfl_xor(a1y, 32, 64);
  a1z += __shfl_xor(a1z, 16, 64); a1z += __shfl_xor(a1z, 32, 64);
  if (es == 0) {
    s0[v * 16 + u] = a0 * 0.25f;
    s1[v * 48 + u * 3 + 0] = a1x * 0.25f;
    s1[v * 48 + u * 3 + 1] = a1y * 0.25f;
    s1[v * 48 + u * 3 + 2] = a1z * 0.25f;
  }
}

// layer1: one wave per node; lane t owns ch t (A/B) and ch 64+t for t<16 (C/D)
__global__ void k_msg1(const int* __restrict__ rs, const int* __restrict__ eid,
                       const int* __restrict__ src,
                       const float* __restrict__ W,    // (E,160)
                       const float* __restrict__ y0,   // (N,64)
                       const float* __restrict__ y1,   // (N,16,3)
                       const float* __restrict__ ea0, const float* __restrict__ ea1,
                       float* __restrict__ s0,         // (N,80)
                       float* __restrict__ s1) {       // (N,80,3)
  int v = (blockIdx.x * 256 + threadIdx.x) >> 6;
  int t = threadIdx.x & 63;
  int b = rs[v], eend = rs[v + 1];
  const float inv_sq3 = 0.5773502691896258f;
  float a0A = 0.f, a0D = 0.f;
  float aB0 = 0.f, aB1 = 0.f, aB2 = 0.f;
  float aC0 = 0.f, aC1 = 0.f, aC2 = 0.f;
  for (int idx = b; idx < eend; idx++) {
    int e = eid[idx];
    int s = src[e];
    float wa = W[(size_t)e * 160 + t];
    float wb = W[(size_t)e * 160 + 64 + t];
    float g0 = y0[s * 64 + t];
    float c0 = ea0[e];
    float cx = ea1[e * 3 + 0], cy = ea1[e * 3 + 1], cz = ea1[e * 3 + 2];
    a0A += wa * g0 * c0;
    float wg = wb * g0;
    aB0 += wg * cx; aB1 += wg * cy; aB2 += wg * cz;
    if (t < 16) {
      float wc = W[(size_t)e * 160 + 128 + t];
      float wd = W[(size_t)e * 160 + 144 + t];
      float g1x = y1[s * 48 + t * 3 + 0];
      float g1y = y1[s * 48 + t * 3 + 1];
      float g1z = y1[s * 48 + t * 3 + 2];
      a0D += wd * (g1x * cx + g1y * cy + g1z * cz) * inv_sq3;
      aC0 += wc * g1x * c0; aC1 += wc * g1y * c0; aC2 += wc * g1z * c0;
    }
  }
  s0[v * 80 + t] = a0A * 0.25f;
  s1[v * 240 + t * 3 + 0] = aB0 * 0.25f;
  s1[v * 240 + t * 3 + 1] = aB1 * 0.25f;
  s1[v * 240 + t * 3 + 2] = aB2 * 0.25f;
  if (t < 16) {
    s0[v * 80 + 64 + t] = a0D * 0.25f;
    s1[v * 240 + (64 + t) * 3 + 0] = aC0 * 0.25f;
    s1[v * 240 + (64 + t) * 3 + 1] = aC1 * 0.25f;
    s1[v * 240 + (64 + t) * 3 + 2] = aC2 * 0.25f;
  }
}

// final: mid0 only
__global__ void k_msgF(const int* __restrict__ rs, const int* __restrict__ eid,
                       const int* __restrict__ src,
                       const float* __restrict__ W,    // (E,80)
                       const float* __restrict__ y0,   // (N,64)
                       const float* __restrict__ y1,   // (N,16,3)
                       const float* __restrict__ ea0, const float* __restrict__ ea1,
                       float* __restrict__ s0) {       // (N,80)
  int v = (blockIdx.x * 256 + threadIdx.x) >> 6;
  int t = threadIdx.x & 63;
  int b = rs[v], eend = rs[v + 1];
  const float inv_sq3 = 0.5773502691896258f;
  float a0A = 0.f, a0D = 0.f;
  for (int idx = b; idx < eend; idx++) {
    int e = eid[idx];
    int s = src[e];
    float wa = W[(size_t)e * 80 + t];
    float g0 = y0[s * 64 + t];
    float c0 = ea0[e];
    a0A += wa * g0 * c0;
    if (t < 16) {
      float wd = W[(size_t)e * 80 + 64 + t];
      float cx = ea1[e * 3 + 0], cy = ea1[e * 3 + 1], cz = ea1[e * 3 + 2];
      float g1x = y1[s * 48 + t * 3 + 0];
      float g1y = y1[s * 48 + t * 3 + 1];
      float g1z = y1[s * 48 + t * 3 + 2];
      a0D += wd * (g1x * cx + g1y * cy + g1z * cz) * inv_sq3;
    }
  }
  s0[v * 80 + t] = a0A * 0.25f;
  if (t < 16) s0[v * 80 + 64 + t] = a0D * 0.25f;
}

// ---------------------------------------------------------------- epilogues
__global__ void k_epi0(const float* __restrict__ s0,    // (N,16)
                       const float* __restrict__ s1,    // (N,16,3)
                       const float* __restrict__ si0b,  // (N,80)
                       const float* __restrict__ w0,    // (80,16)
                       const float* __restrict__ w1,    // (16,16)
                       float* __restrict__ h0, float* __restrict__ h1) {
  int v = (blockIdx.x * 256 + threadIdx.x) >> 6;
  int t = threadIdx.x & 63;
  float s0r[16];
  #pragma unroll
  for (int k = 0; k < 16; k++) s0r[k] = s0[v * 16 + k];
  float a = 0.f;
  #pragma unroll
  for (int k = 0; k < 16; k++) a += w0[t * 16 + k] * s0r[k];
  float o = si0b[v * 80 + t] + 0.125f * a;
  h0[v * 64 + t] = fmaxf(o, 0.f);
  if (t < 16) {
    float a2 = 0.f;
    #pragma unroll
    for (int k = 0; k < 16; k++) a2 += w0[(64 + t) * 16 + k] * s0r[k];
    float g = fmaxf(si0b[v * 80 + 64 + t] + 0.125f * a2, 0.f);
    #pragma unroll
    for (int m = 0; m < 3; m++) {
      float ac = 0.f;
      #pragma unroll
      for (int vv = 0; vv < 16; vv++) ac += w1[t * 16 + vv] * s1[v * 48 + vv * 3 + m];
      h1[v * 48 + t * 3 + m] = (0.125f * ac) * g;
    }
  }
}

__global__ void k_epi1(const float* __restrict__ s0,    // (N,80)
                       const float* __restrict__ s1,    // (N,80,3)
                       const float* __restrict__ si0b,  // (N,80)
                       const float* __restrict__ si1b,  // (N,16,3)
                       const float* __restrict__ w0,    // (80,80)
                       const float* __restrict__ w1,    // (16,80)
                       float* __restrict__ h0, float* __restrict__ h1) {
  int v = (blockIdx.x * 256 + threadIdx.x) >> 6;
  int t = threadIdx.x & 63;
  const float sc = 0.05590169943749474f;  // 0.5/sqrt(80)
  float a = 0.f;
  for (int k = 0; k < 80; k++) a += w0[t * 80 + k] * s0[v * 80 + k];
  float o = si0b[v * 80 + t] + sc * a;
  h0[v * 64 + t] = fmaxf(o, 0.f);
  if (t < 16) {
    float a2 = 0.f;
    for (int k = 0; k < 80; k++) a2 += w0[(64 + t) * 80 + k] * s0[v * 80 + k];
    float g = fmaxf(si0b[v * 80 + 64 + t] + sc * a2, 0.f);
    #pragma unroll
    for (int m = 0; m < 3; m++) {
      float ac = 0.f;
      for (int vv = 0; vv < 80; vv++) ac += w1[t * 80 + vv] * s1[v * 240 + vv * 3 + m];
      h1[v * 48 + t * 3 + m] = (si1b[v * 48 + t * 3 + m] + sc * ac) * g;
    }
  }
}

__global__ void k_epiF(const float* __restrict__ s0,    // (N,80)
                       const float* __restrict__ si0b,  // (N,1)
                       const float* __restrict__ w0,    // (1,80)
                       const int* __restrict__ batch,
                       float* __restrict__ out) {
  __shared__ float sm[NG];
  int tid = threadIdx.x;
  int n = blockIdx.x * 256 + tid;
  if (tid < NG) sm[tid] = 0.f;
  __syncthreads();
  const float sc = 0.05590169943749474f;  // 0.5/sqrt(80)
  float a = 0.f;
  for (int k = 0; k < 80; k++) a += w0[k] * s0[n * 80 + k];
  float val = si0b[n] + sc * a;
  atomicAdd(&sm[batch[n]], val);
  __syncthreads();
  if (tid < NG) atomicAdd(&out[tid], sm[tid] * 0.03125f);  // /sqrt(1024)
}

// ---------------------------------------------------------------- launch
extern "C" void kernel_launch(void* const* d_in, const int* in_sizes, int n_in,
                              void* d_out, int out_size, void* d_ws, size_t ws_size,
                              hipStream_t stream) {
  const float* x        = (const float*)d_in[0];
  const float* z        = (const float*)d_in[1];
  const float* pos      = (const float*)d_in[2];
  const float* fc0_w1   = (const float*)d_in[3];
  const float* fc0_w2   = (const float*)d_in[4];
  const float* si0_w    = (const float*)d_in[5];
  const float* l0_l1_w  = (const float*)d_in[6];
  const float* l0_l2_w0 = (const float*)d_in[7];
  const float* l0_l2_w1 = (const float*)d_in[8];
  const float* fc1_w1   = (const float*)d_in[9];
  const float* fc1_w2   = (const float*)d_in[10];
  const float* si1_w0   = (const float*)d_in[11];
  const float* si1_w1   = (const float*)d_in[12];
  const float* l1_l1_w0 = (const float*)d_in[13];
  const float* l1_l1_w1 = (const float*)d_in[14];
  const float* l1_l2_w0 = (const float*)d_in[15];
  const float* l1_l2_w1 = (const float*)d_in[16];
  const float* fcf_w1   = (const float*)d_in[17];
  const float* fcf_w2   = (const float*)d_in[18];
  const float* sif_w0   = (const float*)d_in[19];
  const float* lf_l1_w0 = (const float*)d_in[20];
  const float* lf_l1_w1 = (const float*)d_in[21];
  const float* lf_l2_w0 = (const float*)d_in[22];
  const int*   esrc     = (const int*)d_in[23];
  const int*   edst     = (const int*)d_in[24];
  const int*   batch    = (const int*)d_in[25];
  float* out = (float*)d_out;

  // workspace carve (floats)
  float* p = (float*)d_ws;
  float* ea0  = p; p += (size_t)N_EDGES;
  float* ea1  = p; p += (size_t)3 * N_EDGES;
  float* emb  = p; p += (size_t)10 * N_EDGES;
  float* W    = p; p += (size_t)160 * N_EDGES;
  float* si0b = p; p += (size_t)80 * N_NODES;
  float* y0b  = p; p += (size_t)64 * N_NODES;
  float* si1b = p; p += (size_t)48 * N_NODES;
  float* y1b  = p; p += (size_t)48 * N_NODES;
  float* s0   = p; p += (size_t)80 * N_NODES;
  float* s1   = p; p += (size_t)240 * N_NODES;
  float* h0   = p; p += (size_t)64 * N_NODES;
  float* h1   = p; p += (size_t)48 * N_NODES;
  int* cnt   = (int*)p;
  int* rowst = cnt + N_NODES;
  int* eids  = rowst + N_NODES + 1;

  hipMemsetAsync(cnt, 0, N_NODES * sizeof(int), stream);
  hipMemsetAsync(d_out, 0, NG * sizeof(float), stream);

  k_edge_geom<<<N_EDGES / 256, 256, 0, stream>>>(pos, esrc, edst, ea0, ea1, emb, cnt);
  k_scan<<<1, 1024, 0, stream>>>(cnt, rowst);
  k_fill<<<N_EDGES / 256, 256, 0, stream>>>(edst, cnt, eids);

  const int NWG = N_NODES / 4;  // wave-per-node kernels: 4 waves / 256-thread block

  // ---- layer 0
  k_pre0<<<NWG, 256, 0, stream>>>(x, z, si0_w, l0_l1_w, si0b, y0b);
  k_radial<32><<<N_EDGES / 64, 256, 0, stream>>>(emb, fc0_w1, fc0_w2, W);
  k_msg0<<<NWG, 256, 0, stream>>>(rowst, eids, esrc, W, y0b, ea0, ea1, s0, s1);
  k_epi0<<<NWG, 256, 0, stream>>>(s0, s1, si0b, l0_l2_w0, l0_l2_w1, h0, h1);

  // ---- layer 1
  k_pre1<<<NWG, 256, 0, stream>>>(h0, h1, z, si1_w0, si1_w1, l1_l1_w0, l1_l1_w1,
                                  si0b, y0b, si1b, y1b);
  k_radial<160><<<N_EDGES / 64, 256, 0, stream>>>(emb, fc1_w1, fc1_w2, W);
  k_msg1<<<NWG, 256, 0, stream>>>(rowst, eids, esrc, W, y0b, y1b, ea0, ea1, s0, s1);
  k_epi1<<<NWG, 256, 0, stream>>>(s0, s1, si0b, si1b, l1_l2_w0, l1_l2_w1, h0, h1);

  // ---- final layer
  k_preF<<<NWG, 256, 0, stream>>>(h0, h1, z, sif_w0, lf_l1_w0, lf_l1_w1,
                                  si0b, y0b, y1b);
  k_radial<80><<<N_EDGES / 64, 256, 0, stream>>>(emb, fcf_w1, fcf_w2, W);
  k_msgF<<<NWG, 256, 0, stream>>>(rowst, eids, esrc, W, y0b, y1b, ea0, ea1, s0);
  k_epiF<<<N_NODES / 256, 256, 0, stream>>>(s0, si0b, lf_l2_w0, batch, out);
}

// Round 4
// 914.263 us; speedup vs baseline: 1.2009x; 1.0360x over previous
//
#include <hip/hip_runtime.h>

static constexpr int N_NODES = 16384;
static constexpr int N_EDGES = 262144;
static constexpr int NG = 16;

// ---------------------------------------------------------------- geometry (+ degree count)
__global__ void k_edge_geom(const float* __restrict__ pos,
                            const int* __restrict__ src,
                            const int* __restrict__ dst,
                            float* __restrict__ ea0,
                            float* __restrict__ ea1,
                            float* __restrict__ emb,
                            int* __restrict__ cnt) {
  int e = blockIdx.x * 256 + threadIdx.x;
  if (e >= N_EDGES) return;
  int s = src[e], d = dst[e];
  float vx = pos[s * 3 + 0] - pos[d * 3 + 0];
  float vy = pos[s * 3 + 1] - pos[d * 3 + 1];
  float vz = pos[s * 3 + 2] - pos[d * 3 + 2];
  float r = sqrtf(vx * vx + vy * vy + vz * vz + 1e-12f);
  // smooth_transition(r/2): u = r - 2
  float u = r - 2.0f;
  float y = 0.5f * (1.0f - cosf(3.14159265358979323846f * u));
  if (u > 0.0f) y = 0.0f;
  if (u < -1.0f) y = 1.0f;
  ea0[e] = y;
  float f = y * 1.7320508075688772f;  // cut * sqrt(3)
  ea1[e * 3 + 0] = f * (vx / r);
  ea1[e * 3 + 1] = f * (vy / r);
  ea1[e * 3 + 2] = f * (vz / r);
  const float step = 2.0f / 9.0f;
  const float s10 = 3.1622776601683795f;  // sqrt(10)
  #pragma unroll
  for (int j = 0; j < 10; j++) {
    float t = (r - step * (float)j) / step;
    emb[e * 10 + j] = expf(-t * t) * s10;
  }
  atomicAdd(&cnt[d], 1);
}

// ---------------------------------------------------------------- CSR build
__global__ void k_scan(int* cnt_cursor, int* __restrict__ row_start) {
  __shared__ int part[1024];
  int t = threadIdx.x;
  int base = t * 16;
  int loc[16];
  int s = 0;
  #pragma unroll
  for (int i = 0; i < 16; i++) { loc[i] = s; s += cnt_cursor[base + i]; }
  part[t] = s;
  __syncthreads();
  for (int off = 1; off < 1024; off <<= 1) {
    int v = part[t];
    int add = (t >= off) ? part[t - off] : 0;
    __syncthreads();
    part[t] = v + add;
    __syncthreads();
  }
  int excl = part[t] - s;
  #pragma unroll
  for (int i = 0; i < 16; i++) {
    int rs = excl + loc[i];
    row_start[base + i] = rs;
    cnt_cursor[base + i] = rs;
  }
  if (t == 1023) row_start[N_NODES] = part[1023];
}

__global__ void k_fill(const int* __restrict__ dst, int* cursor,
                       int* __restrict__ edge_ids) {
  int e = blockIdx.x * 256 + threadIdx.x;
  if (e < N_EDGES) {
    int p = atomicAdd(&cursor[dst[e]], 1);
    edge_ids[p] = e;
  }
}

// ---------------------------------------------------------------- radial MLP
// One edge per thread. h[100] lives in VGPRs (all indices compile-time via
// full unroll). w1/w2 are indexed wave-uniformly -> compiler emits
// s_load_dwordx16 + v_fmac_f32 with SGPR operand: the hot loop is pure FMA
// issue with zero vector loads, zero LDS, zero barriers.
template <int C>
__global__ __launch_bounds__(256) void k_radial(
    const float* __restrict__ emb,
    const float* __restrict__ w1,   // (10,100)
    const float* __restrict__ w2,   // (100,C)
    float* __restrict__ W) {        // (E,C)
  int e = blockIdx.x * 256 + threadIdx.x;
  float er[10];
  const float2* ep = reinterpret_cast<const float2*>(emb + (size_t)e * 10);
  #pragma unroll
  for (int i = 0; i < 5; i++) {
    float2 v = ep[i];
    er[2 * i] = v.x;
    er[2 * i + 1] = v.y;
  }
  const float inv_s10 = 0.31622776601683794f;  // 1/sqrt(10)
  float h[100];
  #pragma unroll
  for (int k = 0; k < 100; k++) {
    float a = 0.f;
    #pragma unroll
    for (int i = 0; i < 10; i++) a += er[i] * w1[i * 100 + k];
    h[k] = fmaxf(a * inv_s10, 0.f);
  }
  float* Wrow = W + (size_t)e * C;
  for (int ct = 0; ct < C / 16; ct++) {
    float acc[16];
    #pragma unroll
    for (int j = 0; j < 16; j++) acc[j] = 0.f;
    const float* w2t = w2 + ct * 16;
    #pragma unroll
    for (int k = 0; k < 100; k++) {
      float hk = h[k];
      #pragma unroll
      for (int j = 0; j < 16; j++) acc[j] += hk * w2t[k * C + j];
    }
    float4* dst4 = reinterpret_cast<float4*>(Wrow + ct * 16);
    #pragma unroll
    for (int q = 0; q < 4; q++) {
      float4 v;
      v.x = acc[q * 4 + 0] * 0.1f;  // /sqrt(100)
      v.y = acc[q * 4 + 1] * 0.1f;
      v.z = acc[q * 4 + 2] * 0.1f;
      v.w = acc[q * 4 + 3] * 0.1f;
      dst4[q] = v;
    }
  }
}

// ---------------------------------------------------------------- node linears
// layer0: x(N,16) -> si0(N,80), y0(N,16)
__global__ void k_pre0(const float* __restrict__ x, const float* __restrict__ z,
                       const float* __restrict__ si_w,  // (80,16)
                       const float* __restrict__ l1_w,  // (16,16)
                       float* __restrict__ si0b, float* __restrict__ y0b) {
  int v = (blockIdx.x * 256 + threadIdx.x) >> 6;
  int t = threadIdx.x & 63;
  float zv = z[v];
  float xz[16];
  #pragma unroll
  for (int i = 0; i < 16; i++) xz[i] = x[v * 16 + i] * zv;
  float a = 0.f;
  #pragma unroll
  for (int k = 0; k < 16; k++) a += si_w[t * 16 + k] * xz[k];
  si0b[v * 80 + t] = a * 0.25f;
  if (t < 16) {
    float a2 = 0.f, a3 = 0.f;
    #pragma unroll
    for (int k = 0; k < 16; k++) {
      a2 += si_w[(64 + t) * 16 + k] * xz[k];
      a3 += l1_w[t * 16 + k] * xz[k];
    }
    si0b[v * 80 + 64 + t] = a2 * 0.25f;
    y0b[v * 16 + t] = a3 * 0.25f;
  }
}

// layer1: h0(N,64),h1(N,16,3) -> si0(N,80), y0(N,64), si1(N,16,3), y1(N,16,3)
__global__ void k_pre1(const float* __restrict__ h0, const float* __restrict__ h1,
                       const float* __restrict__ z,
                       const float* __restrict__ si_w0,  // (80,64)
                       const float* __restrict__ si_w1,  // (16,16)
                       const float* __restrict__ l1_w0,  // (64,64)
                       const float* __restrict__ l1_w1,  // (16,16)
                       float* __restrict__ si0b, float* __restrict__ y0b,
                       float* __restrict__ si1b, float* __restrict__ y1b) {
  __shared__ float xs[4][64];
  int v = (blockIdx.x * 256 + threadIdx.x) >> 6;
  int w = threadIdx.x >> 6;
  int t = threadIdx.x & 63;
  float zv = z[v];
  xs[w][t] = h0[v * 64 + t] * zv;
  __syncthreads();
  const float* x0 = xs[w];
  float a0 = 0.f, ay = 0.f;
  for (int k = 0; k < 64; k++) {
    float xv = x0[k];
    a0 += si_w0[t * 64 + k] * xv;
    ay += l1_w0[t * 64 + k] * xv;
  }
  si0b[v * 80 + t] = a0 * 0.125f;
  y0b[v * 64 + t] = ay * 0.125f;
  if (t < 16) {
    float a2 = 0.f;
    for (int k = 0; k < 64; k++) a2 += si_w0[(64 + t) * 64 + k] * x0[k];
    si0b[v * 80 + 64 + t] = a2 * 0.125f;
    #pragma unroll
    for (int m = 0; m < 3; m++) {
      float s = 0.f, yy = 0.f;
      #pragma unroll
      for (int vv = 0; vv < 16; vv++) {
        float xv = h1[v * 48 + vv * 3 + m] * zv;
        s += si_w1[t * 16 + vv] * xv;
        yy += l1_w1[t * 16 + vv] * xv;
      }
      si1b[v * 48 + t * 3 + m] = s * 0.25f;
      y1b[v * 48 + t * 3 + m] = yy * 0.25f;
    }
  }
}

// final: h0(N,64),h1(N,16,3) -> si0(N,1), y0(N,64), y1(N,16,3)
__global__ void k_preF(const float* __restrict__ h0, const float* __restrict__ h1,
                       const float* __restrict__ z,
                       const float* __restrict__ si_w0,  // (1,64)
                       const float* __restrict__ l1_w0,  // (64,64)
                       const float* __restrict__ l1_w1,  // (16,16)
                       float* __restrict__ si0b, float* __restrict__ y0b,
                       float* __restrict__ y1b) {
  __shared__ float xs[4][64];
  int v = (blockIdx.x * 256 + threadIdx.x) >> 6;
  int w = threadIdx.x >> 6;
  int t = threadIdx.x & 63;
  float zv = z[v];
  xs[w][t] = h0[v * 64 + t] * zv;
  __syncthreads();
  const float* x0 = xs[w];
  float ay = 0.f;
  for (int k = 0; k < 64; k++) ay += l1_w0[t * 64 + k] * x0[k];
  y0b[v * 64 + t] = ay * 0.125f;
  if (t == 0) {
    float a = 0.f;
    for (int k = 0; k < 64; k++) a += si_w0[k] * x0[k];
    si0b[v] = a * 0.125f;
  }
  if (t < 16) {
    #pragma unroll
    for (int m = 0; m < 3; m++) {
      float yy = 0.f;
      #pragma unroll
      for (int vv = 0; vv < 16; vv++)
        yy += l1_w1[t * 16 + vv] * h1[v * 48 + vv * 3 + m] * zv;
      y1b[v * 48 + t * 3 + m] = yy * 0.25f;
    }
  }
}

// ---------------------------------------------------------------- messages
// layer0: one wave per node, 4 edges in flight (lanes = 4 edge-slots x 16 ch)
__global__ void k_msg0(const int* __restrict__ rs, const int* __restrict__ eid,
                       const int* __restrict__ src,
                       const float* __restrict__ W,    // (E,32)
                       const float* __restrict__ y0,   // (N,16)
                       const float* __restrict__ ea0, const float* __restrict__ ea1,
                       float* __restrict__ s0,         // (N,16)
                       float* __restrict__ s1) {       // (N,16,3)
  int v = (blockIdx.x * 256 + threadIdx.x) >> 6;
  int t = threadIdx.x & 63;
  int u = t & 15, es = t >> 4;
  int b = rs[v], eend = rs[v + 1];
  float a0 = 0.f, a1x = 0.f, a1y = 0.f, a1z = 0.f;
  for (int idx = b + es; idx < eend; idx += 4) {
    int e = eid[idx];
    int s = src[e];
    float wa = W[(size_t)e * 32 + u];
    float wb = W[(size_t)e * 32 + 16 + u];
    float g0 = y0[s * 16 + u];
    float c0 = ea0[e];
    float cx = ea1[e * 3 + 0], cy = ea1[e * 3 + 1], cz = ea1[e * 3 + 2];
    a0 += wa * g0 * c0;
    float wg = wb * g0;
    a1x += wg * cx; a1y += wg * cy; a1z += wg * cz;
  }
  a0  += __shfl_xor(a0, 16, 64);  a0  += __shfl_xor(a0, 32, 64);
  a1x += __shfl_xor(a1x, 16, 64); a1x += __shfl_xor(a1x, 32, 64);
  a1y += __shfl_xor(a1y, 16, 64); a1y += __shfl_xor(a1y, 32, 64);
  a1z += __shfl_xor(a1z, 16, 64); a1z += __shfl_xor(a1z, 32, 64);
  if (es == 0) {
    s0[v * 16 + u] = a0 * 0.25f;
    s1[v * 48 + u * 3 + 0] = a1x * 0.25f;
    s1[v * 48 + u * 3 + 1] = a1y * 0.25f;
    s1[v * 48 + u * 3 + 2] = a1z * 0.25f;
  }
}

// layer1: one wave per node; lane t owns ch t (A/B) and ch 64+t for t<16 (C/D)
__global__ void k_msg1(const int* __restrict__ rs, const int* __restrict__ eid,
                       const int* __restrict__ src,
                       const float* __restrict__ W,    // (E,160)
                       const float* __restrict__ y0,   // (N,64)
                       const float* __restrict__ y1,   // (N,16,3)
                       const float* __restrict__ ea0, const float* __restrict__ ea1,
                       float* __restrict__ s0,         // (N,80)
                       float* __restrict__ s1) {       // (N,80,3)
  int v = (blockIdx.x * 256 + threadIdx.x) >> 6;
  int t = threadIdx.x & 63;
  int b = rs[v], eend = rs[v + 1];
  const float inv_sq3 = 0.5773502691896258f;
  float a0A = 0.f, a0D = 0.f;
  float aB0 = 0.f, aB1 = 0.f, aB2 = 0.f;
  float aC0 = 0.f, aC1 = 0.f, aC2 = 0.f;
  for (int idx = b; idx < eend; idx++) {
    int e = eid[idx];
    int s = src[e];
    float wa = W[(size_t)e * 160 + t];
    float wb = W[(size_t)e * 160 + 64 + t];
    float g0 = y0[s * 64 + t];
    float c0 = ea0[e];
    float cx = ea1[e * 3 + 0], cy = ea1[e * 3 + 1], cz = ea1[e * 3 + 2];
    a0A += wa * g0 * c0;
    float wg = wb * g0;
    aB0 += wg * cx; aB1 += wg * cy; aB2 += wg * cz;
    if (t < 16) {
      float wc = W[(size_t)e * 160 + 128 + t];
      float wd = W[(size_t)e * 160 + 144 + t];
      float g1x = y1[s * 48 + t * 3 + 0];
      float g1y = y1[s * 48 + t * 3 + 1];
      float g1z = y1[s * 48 + t * 3 + 2];
      a0D += wd * (g1x * cx + g1y * cy + g1z * cz) * inv_sq3;
      aC0 += wc * g1x * c0; aC1 += wc * g1y * c0; aC2 += wc * g1z * c0;
    }
  }
  s0[v * 80 + t] = a0A * 0.25f;
  s1[v * 240 + t * 3 + 0] = aB0 * 0.25f;
  s1[v * 240 + t * 3 + 1] = aB1 * 0.25f;
  s1[v * 240 + t * 3 + 2] = aB2 * 0.25f;
  if (t < 16) {
    s0[v * 80 + 64 + t] = a0D * 0.25f;
    s1[v * 240 + (64 + t) * 3 + 0] = aC0 * 0.25f;
    s1[v * 240 + (64 + t) * 3 + 1] = aC1 * 0.25f;
    s1[v * 240 + (64 + t) * 3 + 2] = aC2 * 0.25f;
  }
}

// final: mid0 only
__global__ void k_msgF(const int* __restrict__ rs, const int* __restrict__ eid,
                       const int* __restrict__ src,
                       const float* __restrict__ W,    // (E,80)
                       const float* __restrict__ y0,   // (N,64)
                       const float* __restrict__ y1,   // (N,16,3)
                       const float* __restrict__ ea0, const float* __restrict__ ea1,
                       float* __restrict__ s0) {       // (N,80)
  int v = (blockIdx.x * 256 + threadIdx.x) >> 6;
  int t = threadIdx.x & 63;
  int b = rs[v], eend = rs[v + 1];
  const float inv_sq3 = 0.5773502691896258f;
  float a0A = 0.f, a0D = 0.f;
  for (int idx = b; idx < eend; idx++) {
    int e = eid[idx];
    int s = src[e];
    float wa = W[(size_t)e * 80 + t];
    float g0 = y0[s * 64 + t];
    float c0 = ea0[e];
    a0A += wa * g0 * c0;
    if (t < 16) {
      float wd = W[(size_t)e * 80 + 64 + t];
      float cx = ea1[e * 3 + 0], cy = ea1[e * 3 + 1], cz = ea1[e * 3 + 2];
      float g1x = y1[s * 48 + t * 3 + 0];
      float g1y = y1[s * 48 + t * 3 + 1];
      float g1z = y1[s * 48 + t * 3 + 2];
      a0D += wd * (g1x * cx + g1y * cy + g1z * cz) * inv_sq3;
    }
  }
  s0[v * 80 + t] = a0A * 0.25f;
  if (t < 16) s0[v * 80 + 64 + t] = a0D * 0.25f;
}

// ---------------------------------------------------------------- epilogues
__global__ void k_epi0(const float* __restrict__ s0,    // (N,16)
                       const float* __restrict__ s1,    // (N,16,3)
                       const float* __restrict__ si0b,  // (N,80)
                       const float* __restrict__ w0,    // (80,16)
                       const float* __restrict__ w1,    // (16,16)
                       float* __restrict__ h0, float* __restrict__ h1) {
  int v = (blockIdx.x * 256 + threadIdx.x) >> 6;
  int t = threadIdx.x & 63;
  float s0r[16];
  #pragma unroll
  for (int k = 0; k < 16; k++) s0r[k] = s0[v * 16 + k];
  float a = 0.f;
  #pragma unroll
  for (int k = 0; k < 16; k++) a += w0[t * 16 + k] * s0r[k];
  float o = si0b[v * 80 + t] + 0.125f * a;
  h0[v * 64 + t] = fmaxf(o, 0.f);
  if (t < 16) {
    float a2 = 0.f;
    #pragma unroll
    for (int k = 0; k < 16; k++) a2 += w0[(64 + t) * 16 + k] * s0r[k];
    float g = fmaxf(si0b[v * 80 + 64 + t] + 0.125f * a2, 0.f);
    #pragma unroll
    for (int m = 0; m < 3; m++) {
      float ac = 0.f;
      #pragma unroll
      for (int vv = 0; vv < 16; vv++) ac += w1[t * 16 + vv] * s1[v * 48 + vv * 3 + m];
      h1[v * 48 + t * 3 + m] = (0.125f * ac) * g;
    }
  }
}

__global__ void k_epi1(const float* __restrict__ s0,    // (N,80)
                       const float* __restrict__ s1,    // (N,80,3)
                       const float* __restrict__ si0b,  // (N,80)
                       const float* __restrict__ si1b,  // (N,16,3)
                       const float* __restrict__ w0,    // (80,80)
                       const float* __restrict__ w1,    // (16,80)
                       float* __restrict__ h0, float* __restrict__ h1) {
  int v = (blockIdx.x * 256 + threadIdx.x) >> 6;
  int t = threadIdx.x & 63;
  const float sc = 0.05590169943749474f;  // 0.5/sqrt(80)
  float a = 0.f;
  for (int k = 0; k < 80; k++) a += w0[t * 80 + k] * s0[v * 80 + k];
  float o = si0b[v * 80 + t] + sc * a;
  h0[v * 64 + t] = fmaxf(o, 0.f);
  if (t < 16) {
    float a2 = 0.f;
    for (int k = 0; k < 80; k++) a2 += w0[(64 + t) * 80 + k] * s0[v * 80 + k];
    float g = fmaxf(si0b[v * 80 + 64 + t] + sc * a2, 0.f);
    #pragma unroll
    for (int m = 0; m < 3; m++) {
      float ac = 0.f;
      for (int vv = 0; vv < 80; vv++) ac += w1[t * 80 + vv] * s1[v * 240 + vv * 3 + m];
      h1[v * 48 + t * 3 + m] = (si1b[v * 48 + t * 3 + m] + sc * ac) * g;
    }
  }
}

__global__ void k_epiF(const float* __restrict__ s0,    // (N,80)
                       const float* __restrict__ si0b,  // (N,1)
                       const float* __restrict__ w0,    // (1,80)
                       const int* __restrict__ batch,
                       float* __restrict__ out) {
  __shared__ float sm[NG];
  int tid = threadIdx.x;
  int n = blockIdx.x * 256 + tid;
  if (tid < NG) sm[tid] = 0.f;
  __syncthreads();
  const float sc = 0.05590169943749474f;  // 0.5/sqrt(80)
  float a = 0.f;
  for (int k = 0; k < 80; k++) a += w0[k] * s0[n * 80 + k];
  float val = si0b[n] + sc * a;
  atomicAdd(&sm[batch[n]], val);
  __syncthreads();
  if (tid < NG) atomicAdd(&out[tid], sm[tid] * 0.03125f);  // /sqrt(1024)
}

// ---------------------------------------------------------------- launch
extern "C" void kernel_launch(void* const* d_in, const int* in_sizes, int n_in,
                              void* d_out, int out_size, void* d_ws, size_t ws_size,
                              hipStream_t stream) {
  const float* x        = (const float*)d_in[0];
  const float* z        = (const float*)d_in[1];
  const float* pos      = (const float*)d_in[2];
  const float* fc0_w1   = (const float*)d_in[3];
  const float* fc0_w2   = (const float*)d_in[4];
  const float* si0_w    = (const float*)d_in[5];
  const float* l0_l1_w  = (const float*)d_in[6];
  const float* l0_l2_w0 = (const float*)d_in[7];
  const float* l0_l2_w1 = (const float*)d_in[8];
  const float* fc1_w1   = (const float*)d_in[9];
  const float* fc1_w2   = (const float*)d_in[10];
  const float* si1_w0   = (const float*)d_in[11];
  const float* si1_w1   = (const float*)d_in[12];
  const float* l1_l1_w0 = (const float*)d_in[13];
  const float* l1_l1_w1 = (const float*)d_in[14];
  const float* l1_l2_w0 = (const float*)d_in[15];
  const float* l1_l2_w1 = (const float*)d_in[16];
  const float* fcf_w1   = (const float*)d_in[17];
  const float* fcf_w2   = (const float*)d_in[18];
  const float* sif_w0   = (const float*)d_in[19];
  const float* lf_l1_w0 = (const float*)d_in[20];
  const float* lf_l1_w1 = (const float*)d_in[21];
  const float* lf_l2_w0 = (const float*)d_in[22];
  const int*   esrc     = (const int*)d_in[23];
  const int*   edst     = (const int*)d_in[24];
  const int*   batch    = (const int*)d_in[25];
  float* out = (float*)d_out;

  // workspace carve (floats)
  float* p = (float*)d_ws;
  float* ea0  = p; p += (size_t)N_EDGES;
  float* ea1  = p; p += (size_t)3 * N_EDGES;
  float* emb  = p; p += (size_t)10 * N_EDGES;
  float* W    = p; p += (size_t)160 * N_EDGES;
  float* si0b = p; p += (size_t)80 * N_NODES;
  float* y0b  = p; p += (size_t)64 * N_NODES;
  float* si1b = p; p += (size_t)48 * N_NODES;
  float* y1b  = p; p += (size_t)48 * N_NODES;
  float* s0   = p; p += (size_t)80 * N_NODES;
  float* s1   = p; p += (size_t)240 * N_NODES;
  float* h0   = p; p += (size_t)64 * N_NODES;
  float* h1   = p; p += (size_t)48 * N_NODES;
  int* cnt   = (int*)p;
  int* rowst = cnt + N_NODES;
  int* eids  = rowst + N_NODES + 1;

  hipMemsetAsync(cnt, 0, N_NODES * sizeof(int), stream);
  hipMemsetAsync(d_out, 0, NG * sizeof(float), stream);

  k_edge_geom<<<N_EDGES / 256, 256, 0, stream>>>(pos, esrc, edst, ea0, ea1, emb, cnt);
  k_scan<<<1, 1024, 0, stream>>>(cnt, rowst);
  k_fill<<<N_EDGES / 256, 256, 0, stream>>>(edst, cnt, eids);

  const int NWG = N_NODES / 4;  // wave-per-node kernels: 4 waves / 256-thread block

  // ---- layer 0
  k_pre0<<<NWG, 256, 0, stream>>>(x, z, si0_w, l0_l1_w, si0b, y0b);
  k_radial<32><<<N_EDGES / 256, 256, 0, stream>>>(emb, fc0_w1, fc0_w2, W);
  k_msg0<<<NWG, 256, 0, stream>>>(rowst, eids, esrc, W, y0b, ea0, ea1, s0, s1);
  k_epi0<<<NWG, 256, 0, stream>>>(s0, s1, si0b, l0_l2_w0, l0_l2_w1, h0, h1);

  // ---- layer 1
  k_pre1<<<NWG, 256, 0, stream>>>(h0, h1, z, si1_w0, si1_w1, l1_l1_w0, l1_l1_w1,
                                  si0b, y0b, si1b, y1b);
  k_radial<160><<<N_EDGES / 256, 256, 0, stream>>>(emb, fc1_w1, fc1_w2, W);
  k_msg1<<<NWG, 256, 0, stream>>>(rowst, eids, esrc, W, y0b, y1b, ea0, ea1, s0, s1);
  k_epi1<<<NWG, 256, 0, stream>>>(s0, s1, si0b, si1b, l1_l2_w0, l1_l2_w1, h0, h1);

  // ---- final layer
  k_preF<<<NWG, 256, 0, stream>>>(h0, h1, z, sif_w0, lf_l1_w0, lf_l1_w1,
                                  si0b, y0b, y1b);
  k_radial<80><<<N_EDGES / 256, 256, 0, stream>>>(emb, fcf_w1, fcf_w2, W);
  k_msgF<<<NWG, 256, 0, stream>>>(rowst, eids, esrc, W, y0b, y1b, ea0, ea1, s0);
  k_epiF<<<N_NODES / 256, 256, 0, stream>>>(s0, si0b, lf_l2_w0, batch, out);
}